// Round 6
// baseline (189.401 us; speedup 1.0000x reference)
//
#include <hip/hip_runtime.h>
#include <hip/hip_bf16.h>

#define B_ 32
#define T_ 2048
#define D_ 1024
#define A_ 128

typedef __attribute__((ext_vector_type(8))) short bf16x8;
typedef __attribute__((ext_vector_type(4))) float f32x4;

static __device__ __forceinline__ unsigned short f2bf(float f) {
  union { float f; unsigned u; } v; v.f = f;
  unsigned r = v.u + 0x7FFFu + ((v.u >> 16) & 1u);
  return (unsigned short)(r >> 16);
}

// packed f32x2 -> bf16x2 (RNE); compiler emits v_cvt_pk_bf16_f32
static __device__ __forceinline__ unsigned cvt2u(float lo, float hi) {
  __hip_bfloat162 h2 = __float22bfloat162_rn(make_float2(lo, hi));
  unsigned u;
  __builtin_memcpy(&u, &h2, 4);
  return u;
}

// lgkm-only barrier: LDS visibility without draining vmcnt (loads are reg-destined;
// their consumption is enforced by data deps -> compiler emits COUNTED vmcnt)
static __device__ __forceinline__ void barrier_lds() {
  asm volatile("s_waitcnt lgkmcnt(0)\n\ts_barrier" ::: "memory");
}

// ---------------- prep: Wt[a][d] = bf16(Ws[d][a]) ----------------
__global__ __launch_bounds__(256) void k_prep(const float* __restrict__ Ws,
                                              unsigned short* __restrict__ Wt) {
  int i = blockIdx.x * 256 + threadIdx.x;  // coalesced write
  int a = i >> 10, d = i & 1023;
  Wt[i] = f2bf(Ws[(size_t)d * A_ + a]);
}

// ---------------- fused: scores -> exp -> weighted x accumulation ----------------
// grid (8, 32): blockIdx.x = t-slice (256 t), blockIdx.y = b. 512 thr (8 waves), 1 blk/CU.
// 2-deep register pipeline: loads for chunk i+2 issued during chunk i (1.5 chunks of
// flight time, HBM never idles). Loop barriers are lgkm-only; the stage-write's wait is
// a counted vmcnt(8). NO min-occupancy in launch_bounds (r4: (512,2) -> 128-VGPR cap ->
// scratch spills; live set here ~220 VGPR: wreg 128 + stA/stB 64 + misc).
#define LDRF 1028  // f32 row stride (4112 B): +16B pad, conflict-free b128/b64
#define LDRB 1032  // bf16 row stride in shorts (2064 B): +16B pad

__global__ __launch_bounds__(512) void k_fused(const float* __restrict__ x,
                                               const unsigned short* __restrict__ Wt,
                                               const float* __restrict__ bs,
                                               const float* __restrict__ us,
                                               float* __restrict__ part,
                                               float* __restrict__ Zp) {
  __shared__ __align__(16) float xb[16 * LDRF];            // 65,792 B (exact f32 chunk)
  __shared__ __align__(16) unsigned short ab[16 * LDRB];   // 33,024 B (bf16 A-buffer)
  __shared__ float sc_part[16 * 8];
  __shared__ float e_lds[16];

  const int tid  = threadIdx.x;
  const int w    = tid >> 6;
  const int lane = tid & 63;
  const int lrow = lane & 15;
  const int g    = lane >> 4;
  const int sub  = blockIdx.x;
  const int b    = blockIdx.y;

  // W^T fragments for this wave's 16 a-columns, register-resident (128 VGPR)
  const int a_col = w * 16 + lrow;
  bf16x8 wreg[32];
  {
    const unsigned short* wr = Wt + (size_t)a_col * D_ + g * 8;
#pragma unroll
    for (int kt = 0; kt < 32; ++kt) wreg[kt] = *(const bf16x8*)(wr + kt * 32);
  }
  const float bsv = bs[a_col];
  const float usv = us[a_col];

  // staging: thread owns row srow, 8 float4 at cols scol + q*128 (512B/seg coalesced)
  const int srow = w * 2 + (lane >> 5);
  const int scol = (lane & 31) * 4;
  const float* gx = x + ((size_t)b * T_ + (size_t)sub * 256) * D_;

  float4 stA[8], stB[8];

#define ISSUE(dst, ci)                                                            \
  {                                                                               \
    const float* gp_ = gx + (size_t)(ci) * 16 * D_ + (size_t)srow * D_ + scol;    \
    _Pragma("unroll") for (int q = 0; q < 8; ++q)                                 \
        dst[q] = *(const float4*)(gp_ + q * 128);                                 \
  }

#define WRITE_AB(src)                                                             \
  {                                                                               \
    _Pragma("unroll") for (int q = 0; q < 8; ++q) {                               \
      *(float4*)(&xb[srow * LDRF + scol + q * 128]) = src[q];                     \
      unsigned lo_ = cvt2u(src[q].x, src[q].y);                                   \
      unsigned hi_ = cvt2u(src[q].z, src[q].w);                                   \
      *(uint2*)(&ab[srow * LDRB + scol + q * 128]) = make_uint2(lo_, hi_);        \
    }                                                                             \
  }

// Process the chunk currently resident in xb/ab: GEMM -> score -> e -> accumulate.
// C layout: col = lane&15 (a), row = g*4 + r (t). |score| <= ||us||_1 ~ 9 => exp safe.
#define CHUNK_BODY()                                                              \
  {                                                                               \
    f32x4 accm = (f32x4)0.f;                                                      \
    const unsigned short* arow = ab + lrow * LDRB + g * 8;                        \
    _Pragma("unroll") for (int kt = 0; kt < 32; ++kt) {                           \
      bf16x8 af = *(const bf16x8*)(arow + kt * 32);                               \
      accm = __builtin_amdgcn_mfma_f32_16x16x32_bf16(af, wreg[kt], accm, 0, 0, 0);\
    }                                                                             \
    _Pragma("unroll") for (int r = 0; r < 4; ++r) {                               \
      float p = usv * tanhf(accm[r] + bsv);                                       \
      _Pragma("unroll") for (int o = 1; o < 16; o <<= 1)                          \
          p += __shfl_xor(p, o, 64);                                              \
      if (lrow == 0) sc_part[(g * 4 + r) * 8 + w] = p;                            \
    }                                                                             \
    barrier_lds();                                                                \
    if (tid < 16) {                                                               \
      float s_ = 0.f;                                                             \
      _Pragma("unroll") for (int ww = 0; ww < 8; ++ww) s_ += sc_part[tid * 8 + ww];\
      e_lds[tid] = expf(s_);                                                      \
    }                                                                             \
    barrier_lds();                                                                \
    const float* xd = xb + tid * 2;                                               \
    _Pragma("unroll") for (int t = 0; t < 16; ++t) {                              \
      const float2 v_ = *(const float2*)(xd + t * LDRF);                          \
      const float ev_ = e_lds[t];                                                 \
      a0 = fmaf(ev_, v_.x, a0);                                                   \
      a1 = fmaf(ev_, v_.y, a1);                                                   \
      zacc += ev_;                                                                \
    }                                                                             \
  }

  float a0 = 0.f, a1 = 0.f, zacc = 0.f;

  // prologue: chunks 0,1 in flight; stage chunk 0 (compiler waits vmcnt(8))
  ISSUE(stA, 0);
  ISSUE(stB, 1);
  __builtin_amdgcn_sched_barrier(0);
  WRITE_AB(stA);
  barrier_lds();

  for (int i = 0; i < 16; i += 2) {
    // ---- even chunk i: LDS holds i, stB = chunk i+1 in flight, stA free ----
    if (i + 2 < 16) ISSUE(stA, i + 2);
    __builtin_amdgcn_sched_barrier(0);
    CHUNK_BODY();            // consume chunk i
    barrier_lds();           // all reads of chunk i complete
    WRITE_AB(stB);           // stage chunk i+1 (counted vmcnt, i+2 stays in flight)
    barrier_lds();

    // ---- odd chunk i+1: LDS holds i+1, stA = chunk i+2 in flight, stB free ----
    if (i + 3 < 16) ISSUE(stB, i + 3);
    __builtin_amdgcn_sched_barrier(0);
    CHUNK_BODY();            // consume chunk i+1
    barrier_lds();
    if (i + 2 < 16) WRITE_AB(stA);  // stage chunk i+2
    barrier_lds();
  }

  float* pp = part + ((size_t)sub * B_ + b) * D_ + tid * 2;
  *(float2*)pp = make_float2(a0, a1);
  if (tid == 0) Zp[b * 8 + sub] = zacc;
#undef ISSUE
#undef WRITE_AB
#undef CHUNK_BODY
}

// ---------------- reduce 8 slice-partials, divide by Z ----------------
__global__ __launch_bounds__(256) void k_reduce(const float* __restrict__ part,
                                                const float* __restrict__ Zp,
                                                float* __restrict__ out) {
  const int i = blockIdx.x * 256 + threadIdx.x;  // 0..32767
  const int b = i >> 10, d = i & 1023;
  float zs = 0.f;
#pragma unroll
  for (int s = 0; s < 8; ++s) zs += Zp[b * 8 + s];
  float acc = 0.f;
#pragma unroll
  for (int s = 0; s < 8; ++s) acc += part[((size_t)s * B_ + b) * D_ + d];
  out[i] = acc / zs;
}

extern "C" void kernel_launch(void* const* d_in, const int* in_sizes, int n_in,
                              void* d_out, int out_size, void* d_ws, size_t ws_size,
                              hipStream_t stream) {
  const float* x  = (const float*)d_in[0];
  const float* Ws = (const float*)d_in[1];
  const float* bs = (const float*)d_in[2];
  const float* us = (const float*)d_in[3];
  float* out = (float*)d_out;

  char* ws = (char*)d_ws;
  unsigned short* Wt = (unsigned short*)ws;                 // 256 KB
  float* part = (float*)(ws + (256 << 10));                 // 1 MB
  float* Zp   = (float*)(ws + (256 << 10) + (1 << 20));     // 1 KB

  k_prep<<<512, 256, 0, stream>>>(Ws, Wt);
  k_fused<<<dim3(8, B_), 512, 0, stream>>>(x, Wt, bs, us, part, Zp);
  k_reduce<<<(B_ * D_) / 256, 256, 0, stream>>>(part, Zp, out);
}